// Round 8
// baseline (333.871 us; speedup 1.0000x reference)
//
#include <hip/hip_runtime.h>
#include <math.h>

// ---------------------------------------------------------------------------
// Encoder: GCN(2 layers) + per-graph mean pool + FF MLP on pooled rows + sigmoid
// N=100000 nodes, E=1600000 edges, D=128, G=256 graphs (graph_id sorted)
// Round 8: SpMM still latency-bound (VALU 27%, HBM 40%, half the time stall).
//  - quarter-wave per row: 16 lanes x uint4(16B) covers the 256B row; 4 rows
//    per wave => 4 independent gather streams/wave, half the VMEM instrs.
//  - nontemporal loads for ep + nontemporal stores for S: stop streaming
//    traffic from evicting gatherable X lines out of the 4MB/XCD L2.
// ---------------------------------------------------------------------------

#define D 128
#define G 256
#define NB 512     // dst buckets (rows-per-bucket = ceil(N/NB) = 196 <= 256)
#define NBLK 512   // scatter blocks (each owns a contiguous edge chunk)

typedef __attribute__((ext_vector_type(8))) short bf16x8;
typedef __attribute__((ext_vector_type(4))) float f32x4;

__device__ __forceinline__ unsigned short f2bf(float f) {
    unsigned u = __float_as_uint(f);
    unsigned r = (u + 0x7fffu + ((u >> 16) & 1u)) >> 16;   // round-nearest-even
    return (unsigned short)r;
}

// ---- one-time: WT[c][k] = bf16(W[k][c])  (128x128)
__global__ __launch_bounds__(256)
void prep_wt(const float* __restrict__ W, short* __restrict__ WT) {
    int idx = blockIdx.x * 256 + threadIdx.x;
    if (idx >= 128 * 128) return;
    int k = idx >> 7, c = idx & 127;
    WT[c * 128 + k] = (short)f2bf(W[k * 128 + c]);
}

// ---- MFMA GEMM: Y_bf16[nrows x 128] = transform(X_f32) @ W  (WT = W^T bf16)
template<bool BIAS_RELU>
__global__ __launch_bounds__(256, 2)
void gemm_mfma(const float* __restrict__ X, const short* __restrict__ WT,
               const float* __restrict__ bias, short* __restrict__ Y, int nrows) {
    const int lane = threadIdx.x & 63;
    const int lr = lane & 15;        // node-within-group / WT row-within-tile
    const int lq = lane >> 4;        // quarter-wave: k-block selector
    const int wid = blockIdx.x * 4 + (threadIdx.x >> 6);
    const int nwaves = gridDim.x * 4;
    const int ngroups = (nrows + 15) >> 4;

    bf16x8 wf[8][4];
#pragma unroll
    for (int mt = 0; mt < 8; mt++)
#pragma unroll
        for (int ks = 0; ks < 4; ks++)
            wf[mt][ks] = *(const bf16x8*)(WT + (mt * 16 + lr) * 128 + ks * 32 + lq * 8);

    float4 bv0[4], bv1[4];
    if (BIAS_RELU) {
#pragma unroll
        for (int ks = 0; ks < 4; ks++) {
            bv0[ks] = *(const float4*)(bias + ks * 32 + lq * 8);
            bv1[ks] = *(const float4*)(bias + ks * 32 + lq * 8 + 4);
        }
    }

    for (int g = wid; g < ngroups; g += nwaves) {
        int node = g * 16 + lr;
        int nrow = min(node, nrows - 1);
        const float* xp = X + (size_t)nrow * D + lq * 8;
        f32x4 acc[8];
#pragma unroll
        for (int mt = 0; mt < 8; mt++) acc[mt] = (f32x4){0.f, 0.f, 0.f, 0.f};

#pragma unroll
        for (int ks = 0; ks < 4; ks++) {
            float4 v0 = *(const float4*)(xp + ks * 32);
            float4 v1 = *(const float4*)(xp + ks * 32 + 4);
            if (BIAS_RELU) {
                v0.x = fmaxf(v0.x + bv0[ks].x, 0.f);
                v0.y = fmaxf(v0.y + bv0[ks].y, 0.f);
                v0.z = fmaxf(v0.z + bv0[ks].z, 0.f);
                v0.w = fmaxf(v0.w + bv0[ks].w, 0.f);
                v1.x = fmaxf(v1.x + bv1[ks].x, 0.f);
                v1.y = fmaxf(v1.y + bv1[ks].y, 0.f);
                v1.z = fmaxf(v1.z + bv1[ks].z, 0.f);
                v1.w = fmaxf(v1.w + bv1[ks].w, 0.f);
            }
            bf16x8 xb;
            xb[0] = (short)f2bf(v0.x);
            xb[1] = (short)f2bf(v0.y);
            xb[2] = (short)f2bf(v0.z);
            xb[3] = (short)f2bf(v0.w);
            xb[4] = (short)f2bf(v1.x);
            xb[5] = (short)f2bf(v1.y);
            xb[6] = (short)f2bf(v1.z);
            xb[7] = (short)f2bf(v1.w);
#pragma unroll
            for (int mt = 0; mt < 8; mt++)
                acc[mt] = __builtin_amdgcn_mfma_f32_16x16x32_bf16(wf[mt][ks], xb, acc[mt], 0, 0, 0);
        }

        if (node < nrows) {
            short* yp = Y + (size_t)node * D + lq * 4;
#pragma unroll
            for (int mt = 0; mt < 8; mt++) {
                ushort4 o;
                o.x = f2bf(acc[mt][0]);
                o.y = f2bf(acc[mt][1]);
                o.z = f2bf(acc[mt][2]);
                o.w = f2bf(acc[mt][3]);
                *(ushort4*)(yp + mt * 16) = o;
            }
        }
    }
}

// ============== CSR build: atomic-free radix partition + bucket sort ========

__global__ __launch_bounds__(256)
void radix_count(const int* __restrict__ dst, int* __restrict__ counts,
                 int ne, int rpb, int chunk) {
    __shared__ int h[NB];
    for (int i = threadIdx.x; i < NB; i += 256) h[i] = 0;
    __syncthreads();
    int b = blockIdx.x;
    int lo = b * chunk, hi = min(lo + chunk, ne);
    for (int e = lo + threadIdx.x; e < hi; e += 256)
        atomicAdd(&h[dst[e] / rpb], 1);
    __syncthreads();
    for (int k = threadIdx.x; k < NB; k += 256)
        counts[k * NBLK + b] = h[k];
}

__global__ __launch_bounds__(256)
void radix_scan_rel(int* __restrict__ counts, int* __restrict__ bsum) {
    __shared__ int s[256];
    int k = blockIdx.x, t = threadIdx.x;
    int base = k * NBLK + t * 2;
    int v0 = counts[base], v1 = counts[base + 1];
    int sum = v0 + v1;
    s[t] = sum;
    __syncthreads();
    for (int off = 1; off < 256; off <<= 1) {
        int x = (t >= off) ? s[t - off] : 0;
        __syncthreads();
        s[t] += x;
        __syncthreads();
    }
    int ex = s[t] - sum;
    counts[base] = ex;
    counts[base + 1] = ex + v0;
    if (t == 255) bsum[k] = s[255];
}

__global__ __launch_bounds__(NB)
void radix_base(const int* __restrict__ bsum, int* __restrict__ bbase,
                int* __restrict__ row_ptr, int ne, int n) {
    __shared__ int s[NB];
    int t = threadIdx.x;
    int v = bsum[t];
    s[t] = v;
    __syncthreads();
    for (int off = 1; off < NB; off <<= 1) {
        int x = (t >= off) ? s[t - off] : 0;
        __syncthreads();
        s[t] += x;
        __syncthreads();
    }
    bbase[t + 1] = s[t];
    if (t == 0) { bbase[0] = 0; row_ptr[n] = ne; }
}

__global__ __launch_bounds__(256)
void radix_scatter(const int* __restrict__ src, const int* __restrict__ dst,
                   const float* __restrict__ ew,
                   const int* __restrict__ counts, const int* __restrict__ bbase,
                   int2* __restrict__ tmp_sw, unsigned short* __restrict__ tmp_lr,
                   int ne, int rpb, int chunk) {
    __shared__ int cur[NB];
    int b = blockIdx.x;
    for (int k = threadIdx.x; k < NB; k += 256)
        cur[k] = bbase[k] + counts[k * NBLK + b];
    __syncthreads();
    int lo = b * chunk, hi = min(lo + chunk, ne);
    for (int e = lo + threadIdx.x; e < hi; e += 256) {
        int d = dst[e];
        int k = d / rpb;
        int pos = atomicAdd(&cur[k], 1);          // LDS atomic
        tmp_sw[pos] = make_int2(src[e], __float_as_int(ew[e]));
        tmp_lr[pos] = (unsigned short)(d - k * rpb);
    }
}

__global__ __launch_bounds__(256)
void bucket_sort(const unsigned short* __restrict__ tmp_lr,
                 const int2* __restrict__ tmp_sw,
                 const int* __restrict__ bbase, int2* __restrict__ ep,
                 int* __restrict__ row_ptr, int n, int rpb) {
    __shared__ int cnt[256], scn[256], cur[256];
    int b = blockIdx.x, t = threadIdx.x;
    int e0 = bbase[b], e1 = bbase[b + 1];
    int r0 = b * rpb;
    cnt[t] = 0;
    __syncthreads();
    for (int i = e0 + t; i < e1; i += 256)
        atomicAdd(&cnt[tmp_lr[i]], 1);
    __syncthreads();
    int v = cnt[t];
    scn[t] = v;
    __syncthreads();
    for (int off = 1; off < 256; off <<= 1) {
        int x = (t >= off) ? scn[t - off] : 0;
        __syncthreads();
        scn[t] += x;
        __syncthreads();
    }
    int ex = scn[t] - v;
    cur[t] = ex;
    int grow = r0 + t;
    if (t < rpb && grow < n) row_ptr[grow] = e0 + ex;
    __syncthreads();
    for (int i = e0 + t; i < e1; i += 256) {
        int r = tmp_lr[i];
        int pos = e0 + atomicAdd(&cur[r], 1);     // LDS atomic
        ep[pos] = tmp_sw[i];
    }
}

// ---- Gather SpMM: quarter-wave (16 lanes x uint4 = 256B) per row.
// Metadata coalesced-preloaded per 16-edge tile (nontemporal), __shfl w16
// broadcast; 4 rows/wave => 4 independent gather streams; nontemporal store.
__global__ __launch_bounds__(256)
void spmm_csr_bf16(const uint4* __restrict__ Xu4, const long long* __restrict__ ep,
                   const int* __restrict__ rp, float* __restrict__ out, int nrows) {
    int row = blockIdx.x * 16 + (threadIdx.x >> 4);
    if (row >= nrows) return;
    int l = threadIdx.x & 15;             // dim-octet index (8 dims)
    int beg = rp[row], end = rp[row + 1];
    float a0 = 0.f, a1 = 0.f, a2 = 0.f, a3 = 0.f,
          a4 = 0.f, a5 = 0.f, a6 = 0.f, a7 = 0.f;

    for (int t0 = beg; t0 < end; t0 += 16) {
        int j = t0 + l;
        long long epk = (j < end) ? __builtin_nontemporal_load(ep + j) : 0ll;
        int cnt = min(16, end - t0);
#pragma unroll 4
        for (int t = 0; t < cnt; t++) {
            long long ebc = __shfl(epk, t, 16);
            int s = (int)(ebc & 0xffffffffll);
            float w = __uint_as_float((unsigned)((unsigned long long)ebc >> 32));
            uint4 u = Xu4[(size_t)s * 16 + l];
            a0 = fmaf(w, __uint_as_float(u.x << 16), a0);
            a1 = fmaf(w, __uint_as_float(u.x & 0xffff0000u), a1);
            a2 = fmaf(w, __uint_as_float(u.y << 16), a2);
            a3 = fmaf(w, __uint_as_float(u.y & 0xffff0000u), a3);
            a4 = fmaf(w, __uint_as_float(u.z << 16), a4);
            a5 = fmaf(w, __uint_as_float(u.z & 0xffff0000u), a5);
            a6 = fmaf(w, __uint_as_float(u.w << 16), a6);
            a7 = fmaf(w, __uint_as_float(u.w & 0xffff0000u), a7);
        }
    }
    float* op = out + (size_t)row * D + l * 8;
    __builtin_nontemporal_store((f32x4){a0, a1, a2, a3}, (f32x4*)op);
    __builtin_nontemporal_store((f32x4){a4, a5, a6, a7}, (f32x4*)(op + 4));
}

// ======================= graph pooling + FF =================================

__global__ __launch_bounds__(256)
void bounds_kernel(const int* __restrict__ gid, int* __restrict__ ptr, int n) {
    int i = blockIdx.x * 256 + threadIdx.x;
    if (i >= n) return;
    int b = gid[i];
    int a = (i == 0) ? -1 : gid[i - 1];
    for (int g = a + 1; g <= b; g++) ptr[g] = i;
    if (i == n - 1) {
        for (int g = b + 1; g <= G; g++) ptr[g] = n;
    }
}

__global__ __launch_bounds__(512)
void pool_kernel(const float* __restrict__ S, const int* __restrict__ ptr,
                 const float* __restrict__ b2, float* __restrict__ pooled) {
    __shared__ float red[4][128];
    int g = blockIdx.x;
    int d = threadIdx.x & 127;
    int r = threadIdx.x >> 7;
    int beg = ptr[g], end = ptr[g + 1];
    float acc = 0.f;
    for (int n = beg + r; n < end; n += 4) acc += S[(size_t)n * D + d];
    red[r][d] = acc;
    __syncthreads();
    if (r == 0) {
        float s = red[0][d] + red[1][d] + red[2][d] + red[3][d];
        int cnt = end - beg;
        pooled[g * D + d] = (cnt > 0) ? (s / (float)cnt + b2[d]) : 0.f;
    }
}

__global__ __launch_bounds__(128)
void ff_kernel(const float* __restrict__ pooled,
               const float* __restrict__ W1, const float* __restrict__ b1,
               const float* __restrict__ W2, const float* __restrict__ b2,
               const float* __restrict__ W3, const float* __restrict__ b3,
               const float* __restrict__ Wsc, const float* __restrict__ bsc,
               float* __restrict__ ffout) {
    __shared__ float hx[D], za[D], zb[D];
    int g = blockIdx.x, d = threadIdx.x;
    hx[d] = pooled[g * D + d];
    __syncthreads();
    float s = b1[d];
    for (int k = 0; k < D; k++) s = fmaf(hx[k], W1[k * D + d], s);
    za[d] = fmaxf(s, 0.f);
    __syncthreads();
    s = b2[d];
    for (int k = 0; k < D; k++) s = fmaf(za[k], W2[k * D + d], s);
    zb[d] = fmaxf(s, 0.f);
    __syncthreads();
    s = b3[d];
    for (int k = 0; k < D; k++) s = fmaf(zb[k], W3[k * D + d], s);
    float z3 = fmaxf(s, 0.f);
    float sc = bsc[d];
    for (int k = 0; k < D; k++) sc = fmaf(hx[k], Wsc[k * D + d], sc);
    float v = z3 + sc;
    ffout[g * D + d] = 1.f / (1.f + expf(-v));
}

__global__ __launch_bounds__(256)
void scatter_kernel(const float* __restrict__ ffout, const int* __restrict__ gid,
                    float* __restrict__ out, int n) {
    unsigned idx = blockIdx.x * 256u + threadIdx.x;
    unsigned node = idx >> 5;
    if (node >= (unsigned)n) return;
    int d0 = (idx & 31) * 4;
    int g = gid[node];
    *(float4*)(out + (size_t)node * D + d0) = *(const float4*)(ffout + g * D + d0);
}

extern "C" void kernel_launch(void* const* d_in, const int* in_sizes, int n_in,
                              void* d_out, int out_size, void* d_ws, size_t ws_size,
                              hipStream_t stream) {
    const float* feat = (const float*)d_in[0];
    const float* ew   = (const float*)d_in[1];
    const float* W1   = (const float*)d_in[2];
    const float* b1   = (const float*)d_in[3];
    const float* W2   = (const float*)d_in[4];
    const float* b2   = (const float*)d_in[5];
    const float* ffW1 = (const float*)d_in[6];
    const float* ffb1 = (const float*)d_in[7];
    const float* ffW2 = (const float*)d_in[8];
    const float* ffb2 = (const float*)d_in[9];
    const float* ffW3 = (const float*)d_in[10];
    const float* ffb3 = (const float*)d_in[11];
    const float* ffWs = (const float*)d_in[12];
    const float* ffbs = (const float*)d_in[13];
    const int* esrc = (const int*)d_in[14];
    const int* edst = (const int*)d_in[15];
    const int* gid  = (const int*)d_in[16];

    const int N = in_sizes[0] / D;
    const int E = in_sizes[1];
    float* out = (float*)d_out;

    const int rpb = (N + NB - 1) / NB;        // 196 (<=256 required by bucket_sort)
    const int chunk = (E + NBLK - 1) / NBLK;  // edges per scatter block

    // workspace layout
    char* ws = (char*)d_ws;
    int2* ep = (int2*)ws;                                   // E int2 = 12.8MB
    unsigned short* A = (unsigned short*)(ep + E);          // N*128 bf16 = 25.6MB
    // build temporaries alias A (A written only after build completes)
    int2* tmp_sw = (int2*)A;                                // E int2 = 12.8MB
    unsigned short* tmp_lr = (unsigned short*)(tmp_sw + E); // E u16  =  3.2MB
    float* pooled = (float*)(A + (size_t)N * D);            // G*D
    float* ffo = pooled + G * D;                            // G*D
    int* gptr = (int*)(ffo + G * D);                        // G+1
    int* row_ptr = gptr + G + 2;                            // N+1
    int* bbase = row_ptr + N + 1;                           // NB+1
    int* bsum = bbase + NB + 1;                             // NB
    int* counts = bsum + NB;                                // NB*NBLK = 1MB
    short* WT1 = (short*)(counts + NB * NBLK);              // 128*128 bf16
    short* WT2 = WT1 + 128 * 128;                           // 128*128 bf16

    float* S = out;  // fp32 SpMM result buffer

    const dim3 blk(256);
    const int nGrid = (N + 255) / 256;

    // ---- weight transpose+bf16 (tiny, once per call)
    prep_wt<<<64, blk, 0, stream>>>(W1, WT1);
    prep_wt<<<64, blk, 0, stream>>>(W2, WT2);

    // ---- CSR build (atomic-free radix partition; LDS atomics only)
    radix_count<<<NBLK, blk, 0, stream>>>(edst, counts, E, rpb, chunk);
    radix_scan_rel<<<NB, blk, 0, stream>>>(counts, bsum);
    radix_base<<<1, NB, 0, stream>>>(bsum, bbase, row_ptr, E, N);
    radix_scatter<<<NBLK, blk, 0, stream>>>(esrc, edst, ew, counts, bbase,
                                            tmp_sw, tmp_lr, E, rpb, chunk);
    bucket_sort<<<NB, blk, 0, stream>>>(tmp_lr, tmp_sw, bbase, ep, row_ptr, N, rpb);

    // ---- graph boundaries from sorted gid
    bounds_kernel<<<nGrid, blk, 0, stream>>>(gid, gptr, N);

    // ---- pipeline (A stored bf16; S fp32)
    gemm_mfma<false><<<512, blk, 0, stream>>>(feat, WT1, nullptr, (short*)A, N);
    spmm_csr_bf16<<<(N + 15) / 16, blk, 0, stream>>>((const uint4*)A, (const long long*)ep, row_ptr, S, N);
    gemm_mfma<true><<<512, blk, 0, stream>>>(S, WT2, b1, (short*)A, N);
    spmm_csr_bf16<<<(N + 15) / 16, blk, 0, stream>>>((const uint4*)A, (const long long*)ep, row_ptr, S, N);

    // ---- per-graph mean pool + FF + scatter
    pool_kernel<<<G, 512, 0, stream>>>(S, gptr, b2, pooled);
    ff_kernel<<<G, 128, 0, stream>>>(pooled, ffW1, ffb1, ffW2, ffb2,
                                     ffW3, ffb3, ffWs, ffbs, ffo);
    scatter_kernel<<<(int)(((size_t)N * 32 + 255) / 256), blk, 0, stream>>>(ffo, gid, out, N);
}

// Round 10
// 321.457 us; speedup vs baseline: 1.0386x; 1.0386x over previous
//
#include <hip/hip_runtime.h>
#include <math.h>

// ---------------------------------------------------------------------------
// Encoder: GCN(2 layers) + per-graph mean pool + FF MLP on pooled rows + sigmoid
// N=100000 nodes, E=1600000 edges, D=128, G=256 graphs (graph_id sorted)
// Round 10: FIX round-9 store-stride bug in fused spmm1 epilogue:
//   bf16 row = 256B = 16 uint4 -> index must be row*16 + l (was row*4 + l,
//   which overlapped rows 4:1 => absmax 0.37). Rest of r9 design unchanged:
//   - fused relu(.+b1)->bf16 S1 in d_out front half (25.6MB write vs 50MB)
//   - gemm2 = pure bf16-input MFMA GEMM (no cvt, half read bytes)
//   - NT load for ep only; NO NT stores (r8 lesson: S is re-read)
// ---------------------------------------------------------------------------

#define D 128
#define G 256
#define NB 512     // dst buckets (rows-per-bucket = ceil(N/NB) = 196 <= 256)
#define NBLK 512   // scatter blocks (each owns a contiguous edge chunk)

typedef __attribute__((ext_vector_type(8))) short bf16x8;
typedef __attribute__((ext_vector_type(4))) float f32x4;

__device__ __forceinline__ unsigned short f2bf(float f) {
    unsigned u = __float_as_uint(f);
    unsigned r = (u + 0x7fffu + ((u >> 16) & 1u)) >> 16;   // round-nearest-even
    return (unsigned short)r;
}

// ---- one-time: WT[c][k] = bf16(W[k][c]) for both weight matrices
__global__ __launch_bounds__(256)
void prep_wt2(const float* __restrict__ W1, short* __restrict__ WT1,
              const float* __restrict__ W2, short* __restrict__ WT2) {
    int idx = blockIdx.x * 256 + threadIdx.x;
    int m = idx & 16383;
    int k = m >> 7, c = m & 127;
    if (idx < 16384)
        WT1[c * 128 + k] = (short)f2bf(W1[k * 128 + c]);
    else
        WT2[c * 128 + k] = (short)f2bf(W2[k * 128 + c]);
}

// ---- MFMA GEMM (fp32 input): Y_bf16 = X_f32 @ W   (WT = W^T bf16)
__global__ __launch_bounds__(256, 2)
void gemm_mfma_f32in(const float* __restrict__ X, const short* __restrict__ WT,
                     short* __restrict__ Y, int nrows) {
    const int lane = threadIdx.x & 63;
    const int lr = lane & 15;
    const int lq = lane >> 4;
    const int wid = blockIdx.x * 4 + (threadIdx.x >> 6);
    const int nwaves = gridDim.x * 4;
    const int ngroups = (nrows + 15) >> 4;

    bf16x8 wf[8][4];
#pragma unroll
    for (int mt = 0; mt < 8; mt++)
#pragma unroll
        for (int ks = 0; ks < 4; ks++)
            wf[mt][ks] = *(const bf16x8*)(WT + (mt * 16 + lr) * 128 + ks * 32 + lq * 8);

    for (int g = wid; g < ngroups; g += nwaves) {
        int node = g * 16 + lr;
        int nrow = min(node, nrows - 1);
        const float* xp = X + (size_t)nrow * D + lq * 8;
        f32x4 acc[8];
#pragma unroll
        for (int mt = 0; mt < 8; mt++) acc[mt] = (f32x4){0.f, 0.f, 0.f, 0.f};

#pragma unroll
        for (int ks = 0; ks < 4; ks++) {
            float4 v0 = *(const float4*)(xp + ks * 32);
            float4 v1 = *(const float4*)(xp + ks * 32 + 4);
            bf16x8 xb;
            xb[0] = (short)f2bf(v0.x);
            xb[1] = (short)f2bf(v0.y);
            xb[2] = (short)f2bf(v0.z);
            xb[3] = (short)f2bf(v0.w);
            xb[4] = (short)f2bf(v1.x);
            xb[5] = (short)f2bf(v1.y);
            xb[6] = (short)f2bf(v1.z);
            xb[7] = (short)f2bf(v1.w);
#pragma unroll
            for (int mt = 0; mt < 8; mt++)
                acc[mt] = __builtin_amdgcn_mfma_f32_16x16x32_bf16(wf[mt][ks], xb, acc[mt], 0, 0, 0);
        }

        if (node < nrows) {
            short* yp = Y + (size_t)node * D + lq * 4;
#pragma unroll
            for (int mt = 0; mt < 8; mt++) {
                ushort4 o;
                o.x = f2bf(acc[mt][0]);
                o.y = f2bf(acc[mt][1]);
                o.z = f2bf(acc[mt][2]);
                o.w = f2bf(acc[mt][3]);
                *(ushort4*)(yp + mt * 16) = o;
            }
        }
    }
}

// ---- MFMA GEMM (bf16 input): Y_bf16 = X_bf16 @ W  (direct frag loads, no cvt)
__global__ __launch_bounds__(256, 2)
void gemm_mfma_bf16in(const unsigned short* __restrict__ X, const short* __restrict__ WT,
                      short* __restrict__ Y, int nrows) {
    const int lane = threadIdx.x & 63;
    const int lr = lane & 15;
    const int lq = lane >> 4;
    const int wid = blockIdx.x * 4 + (threadIdx.x >> 6);
    const int nwaves = gridDim.x * 4;
    const int ngroups = (nrows + 15) >> 4;

    bf16x8 wf[8][4];
#pragma unroll
    for (int mt = 0; mt < 8; mt++)
#pragma unroll
        for (int ks = 0; ks < 4; ks++)
            wf[mt][ks] = *(const bf16x8*)(WT + (mt * 16 + lr) * 128 + ks * 32 + lq * 8);

    for (int g = wid; g < ngroups; g += nwaves) {
        int node = g * 16 + lr;
        int nrow = min(node, nrows - 1);
        const unsigned short* xp = X + (size_t)nrow * D + lq * 8;
        f32x4 acc[8];
#pragma unroll
        for (int mt = 0; mt < 8; mt++) acc[mt] = (f32x4){0.f, 0.f, 0.f, 0.f};

#pragma unroll
        for (int ks = 0; ks < 4; ks++) {
            bf16x8 xb = *(const bf16x8*)(xp + ks * 32);
#pragma unroll
            for (int mt = 0; mt < 8; mt++)
                acc[mt] = __builtin_amdgcn_mfma_f32_16x16x32_bf16(wf[mt][ks], xb, acc[mt], 0, 0, 0);
        }

        if (node < nrows) {
            short* yp = Y + (size_t)node * D + lq * 4;
#pragma unroll
            for (int mt = 0; mt < 8; mt++) {
                ushort4 o;
                o.x = f2bf(acc[mt][0]);
                o.y = f2bf(acc[mt][1]);
                o.z = f2bf(acc[mt][2]);
                o.w = f2bf(acc[mt][3]);
                *(ushort4*)(yp + mt * 16) = o;
            }
        }
    }
}

// ============== CSR build: atomic-free radix partition + bucket sort ========

__global__ __launch_bounds__(256)
void radix_count(const int* __restrict__ dst, int* __restrict__ counts,
                 int ne, int rpb, int chunk) {
    __shared__ int h[NB];
    for (int i = threadIdx.x; i < NB; i += 256) h[i] = 0;
    __syncthreads();
    int b = blockIdx.x;
    int lo = b * chunk, hi = min(lo + chunk, ne);
    for (int e = lo + threadIdx.x; e < hi; e += 256)
        atomicAdd(&h[dst[e] / rpb], 1);
    __syncthreads();
    for (int k = threadIdx.x; k < NB; k += 256)
        counts[k * NBLK + b] = h[k];
}

__global__ __launch_bounds__(256)
void radix_scan_rel(int* __restrict__ counts, int* __restrict__ bsum) {
    __shared__ int s[256];
    int k = blockIdx.x, t = threadIdx.x;
    int base = k * NBLK + t * 2;
    int v0 = counts[base], v1 = counts[base + 1];
    int sum = v0 + v1;
    s[t] = sum;
    __syncthreads();
    for (int off = 1; off < 256; off <<= 1) {
        int x = (t >= off) ? s[t - off] : 0;
        __syncthreads();
        s[t] += x;
        __syncthreads();
    }
    int ex = s[t] - sum;
    counts[base] = ex;
    counts[base + 1] = ex + v0;
    if (t == 255) bsum[k] = s[255];
}

__global__ __launch_bounds__(NB)
void radix_base(const int* __restrict__ bsum, int* __restrict__ bbase,
                int* __restrict__ row_ptr, int ne, int n) {
    __shared__ int s[NB];
    int t = threadIdx.x;
    int v = bsum[t];
    s[t] = v;
    __syncthreads();
    for (int off = 1; off < NB; off <<= 1) {
        int x = (t >= off) ? s[t - off] : 0;
        __syncthreads();
        s[t] += x;
        __syncthreads();
    }
    bbase[t + 1] = s[t];
    if (t == 0) { bbase[0] = 0; row_ptr[n] = ne; }
}

__global__ __launch_bounds__(256)
void radix_scatter(const int* __restrict__ src, const int* __restrict__ dst,
                   const float* __restrict__ ew,
                   const int* __restrict__ counts, const int* __restrict__ bbase,
                   int2* __restrict__ tmp_sw, unsigned short* __restrict__ tmp_lr,
                   int ne, int rpb, int chunk) {
    __shared__ int cur[NB];
    int b = blockIdx.x;
    for (int k = threadIdx.x; k < NB; k += 256)
        cur[k] = bbase[k] + counts[k * NBLK + b];
    __syncthreads();
    int lo = b * chunk, hi = min(lo + chunk, ne);
    for (int e = lo + threadIdx.x; e < hi; e += 256) {
        int d = dst[e];
        int k = d / rpb;
        int pos = atomicAdd(&cur[k], 1);          // LDS atomic
        tmp_sw[pos] = make_int2(src[e], __float_as_int(ew[e]));
        tmp_lr[pos] = (unsigned short)(d - k * rpb);
    }
}

__global__ __launch_bounds__(256)
void bucket_sort(const unsigned short* __restrict__ tmp_lr,
                 const int2* __restrict__ tmp_sw,
                 const int* __restrict__ bbase, int2* __restrict__ ep,
                 int* __restrict__ row_ptr, int n, int rpb) {
    __shared__ int cnt[256], scn[256], cur[256];
    int b = blockIdx.x, t = threadIdx.x;
    int e0 = bbase[b], e1 = bbase[b + 1];
    int r0 = b * rpb;
    cnt[t] = 0;
    __syncthreads();
    for (int i = e0 + t; i < e1; i += 256)
        atomicAdd(&cnt[tmp_lr[i]], 1);
    __syncthreads();
    int v = cnt[t];
    scn[t] = v;
    __syncthreads();
    for (int off = 1; off < 256; off <<= 1) {
        int x = (t >= off) ? scn[t - off] : 0;
        __syncthreads();
        scn[t] += x;
        __syncthreads();
    }
    int ex = scn[t] - v;
    cur[t] = ex;
    int grow = r0 + t;
    if (t < rpb && grow < n) row_ptr[grow] = e0 + ex;
    __syncthreads();
    for (int i = e0 + t; i < e1; i += 256) {
        int r = tmp_lr[i];
        int pos = e0 + atomicAdd(&cur[r], 1);     // LDS atomic
        ep[pos] = tmp_sw[i];
    }
}

// ---- Gather SpMM: quarter-wave (16 lanes x uint4 = 256B) per row.
// FUSE=true: out = bf16(relu(acc + bias)) packed; else out = fp32 acc.
template<bool FUSE>
__global__ __launch_bounds__(256)
void spmm_csr(const uint4* __restrict__ Xu4, const long long* __restrict__ ep,
              const int* __restrict__ rp, const float* __restrict__ bias,
              void* __restrict__ outv, int nrows) {
    int row = blockIdx.x * 16 + (threadIdx.x >> 4);
    if (row >= nrows) return;
    int l = threadIdx.x & 15;             // dim-octet index (8 dims)
    int beg = rp[row], end = rp[row + 1];
    float a0 = 0.f, a1 = 0.f, a2 = 0.f, a3 = 0.f,
          a4 = 0.f, a5 = 0.f, a6 = 0.f, a7 = 0.f;

    for (int t0 = beg; t0 < end; t0 += 16) {
        int j = t0 + l;
        long long epk = (j < end) ? __builtin_nontemporal_load(ep + j) : 0ll;
        int cnt = min(16, end - t0);
#pragma unroll 8
        for (int t = 0; t < cnt; t++) {
            long long ebc = __shfl(epk, t, 16);
            int s = (int)(ebc & 0xffffffffll);
            float w = __uint_as_float((unsigned)((unsigned long long)ebc >> 32));
            uint4 u = Xu4[(size_t)s * 16 + l];
            a0 = fmaf(w, __uint_as_float(u.x << 16), a0);
            a1 = fmaf(w, __uint_as_float(u.x & 0xffff0000u), a1);
            a2 = fmaf(w, __uint_as_float(u.y << 16), a2);
            a3 = fmaf(w, __uint_as_float(u.y & 0xffff0000u), a3);
            a4 = fmaf(w, __uint_as_float(u.z << 16), a4);
            a5 = fmaf(w, __uint_as_float(u.z & 0xffff0000u), a5);
            a6 = fmaf(w, __uint_as_float(u.w << 16), a6);
            a7 = fmaf(w, __uint_as_float(u.w & 0xffff0000u), a7);
        }
    }
    if (FUSE) {
        // relu(acc + b1) -> packed bf16 (layer-1 epilogue fused)
        const float4 b0 = *(const float4*)(bias + l * 8);
        const float4 b1v = *(const float4*)(bias + l * 8 + 4);
        a0 = fmaxf(a0 + b0.x, 0.f);  a1 = fmaxf(a1 + b0.y, 0.f);
        a2 = fmaxf(a2 + b0.z, 0.f);  a3 = fmaxf(a3 + b0.w, 0.f);
        a4 = fmaxf(a4 + b1v.x, 0.f); a5 = fmaxf(a5 + b1v.y, 0.f);
        a6 = fmaxf(a6 + b1v.z, 0.f); a7 = fmaxf(a7 + b1v.w, 0.f);
        uint4 p;
        p.x = (unsigned)f2bf(a0) | ((unsigned)f2bf(a1) << 16);
        p.y = (unsigned)f2bf(a2) | ((unsigned)f2bf(a3) << 16);
        p.z = (unsigned)f2bf(a4) | ((unsigned)f2bf(a5) << 16);
        p.w = (unsigned)f2bf(a6) | ((unsigned)f2bf(a7) << 16);
        // bf16 row = 256B = 16 uint4  (r9 bug was stride 4)
        *((uint4*)outv + (size_t)row * 16 + l) = p;
    } else {
        float* op = (float*)outv + (size_t)row * D + l * 8;
        *(f32x4*)op = (f32x4){a0, a1, a2, a3};
        *(f32x4*)(op + 4) = (f32x4){a4, a5, a6, a7};
    }
}

// ======================= graph pooling + FF =================================

__global__ __launch_bounds__(256)
void bounds_kernel(const int* __restrict__ gid, int* __restrict__ ptr, int n) {
    int i = blockIdx.x * 256 + threadIdx.x;
    if (i >= n) return;
    int b = gid[i];
    int a = (i == 0) ? -1 : gid[i - 1];
    for (int g = a + 1; g <= b; g++) ptr[g] = i;
    if (i == n - 1) {
        for (int g = b + 1; g <= G; g++) ptr[g] = n;
    }
}

__global__ __launch_bounds__(512)
void pool_kernel(const float* __restrict__ S, const int* __restrict__ ptr,
                 const float* __restrict__ b2, float* __restrict__ pooled) {
    __shared__ float red[4][128];
    int g = blockIdx.x;
    int d = threadIdx.x & 127;
    int r = threadIdx.x >> 7;
    int beg = ptr[g], end = ptr[g + 1];
    float acc = 0.f;
    for (int n = beg + r; n < end; n += 4) acc += S[(size_t)n * D + d];
    red[r][d] = acc;
    __syncthreads();
    if (r == 0) {
        float s = red[0][d] + red[1][d] + red[2][d] + red[3][d];
        int cnt = end - beg;
        pooled[g * D + d] = (cnt > 0) ? (s / (float)cnt + b2[d]) : 0.f;
    }
}

__global__ __launch_bounds__(128)
void ff_kernel(const float* __restrict__ pooled,
               const float* __restrict__ W1, const float* __restrict__ b1,
               const float* __restrict__ W2, const float* __restrict__ b2,
               const float* __restrict__ W3, const float* __restrict__ b3,
               const float* __restrict__ Wsc, const float* __restrict__ bsc,
               float* __restrict__ ffout) {
    __shared__ float hx[D], za[D], zb[D];
    int g = blockIdx.x, d = threadIdx.x;
    hx[d] = pooled[g * D + d];
    __syncthreads();
    float s = b1[d];
    for (int k = 0; k < D; k++) s = fmaf(hx[k], W1[k * D + d], s);
    za[d] = fmaxf(s, 0.f);
    __syncthreads();
    s = b2[d];
    for (int k = 0; k < D; k++) s = fmaf(za[k], W2[k * D + d], s);
    zb[d] = fmaxf(s, 0.f);
    __syncthreads();
    s = b3[d];
    for (int k = 0; k < D; k++) s = fmaf(zb[k], W3[k * D + d], s);
    float z3 = fmaxf(s, 0.f);
    float sc = bsc[d];
    for (int k = 0; k < D; k++) sc = fmaf(hx[k], Wsc[k * D + d], sc);
    float v = z3 + sc;
    ffout[g * D + d] = 1.f / (1.f + expf(-v));
}

__global__ __launch_bounds__(256)
void scatter_kernel(const float* __restrict__ ffout, const int* __restrict__ gid,
                    float* __restrict__ out, int n) {
    unsigned idx = blockIdx.x * 256u + threadIdx.x;
    unsigned node = idx >> 5;
    if (node >= (unsigned)n) return;
    int d0 = (idx & 31) * 4;
    int g = gid[node];
    *(float4*)(out + (size_t)node * D + d0) = *(const float4*)(ffout + g * D + d0);
}

extern "C" void kernel_launch(void* const* d_in, const int* in_sizes, int n_in,
                              void* d_out, int out_size, void* d_ws, size_t ws_size,
                              hipStream_t stream) {
    const float* feat = (const float*)d_in[0];
    const float* ew   = (const float*)d_in[1];
    const float* W1   = (const float*)d_in[2];
    const float* b1   = (const float*)d_in[3];
    const float* W2   = (const float*)d_in[4];
    const float* b2   = (const float*)d_in[5];
    const float* ffW1 = (const float*)d_in[6];
    const float* ffb1 = (const float*)d_in[7];
    const float* ffW2 = (const float*)d_in[8];
    const float* ffb2 = (const float*)d_in[9];
    const float* ffW3 = (const float*)d_in[10];
    const float* ffb3 = (const float*)d_in[11];
    const float* ffWs = (const float*)d_in[12];
    const float* ffbs = (const float*)d_in[13];
    const int* esrc = (const int*)d_in[14];
    const int* edst = (const int*)d_in[15];
    const int* gid  = (const int*)d_in[16];

    const int N = in_sizes[0] / D;
    const int E = in_sizes[1];
    float* out = (float*)d_out;

    const int rpb = (N + NB - 1) / NB;        // 196 (<=256 required by bucket_sort)
    const int chunk = (E + NBLK - 1) / NBLK;  // edges per scatter block

    // workspace layout
    char* ws = (char*)d_ws;
    int2* ep = (int2*)ws;                                   // E int2 = 12.8MB
    unsigned short* A = (unsigned short*)(ep + E);          // N*128 bf16 = 25.6MB
    // build temporaries alias A (A written only after build completes)
    int2* tmp_sw = (int2*)A;                                // E int2 = 12.8MB
    unsigned short* tmp_lr = (unsigned short*)(tmp_sw + E); // E u16  =  3.2MB
    float* pooled = (float*)(A + (size_t)N * D);            // G*D
    float* ffo = pooled + G * D;                            // G*D
    int* gptr = (int*)(ffo + G * D);                        // G+1
    int* row_ptr = gptr + G + 2;                            // N+1
    int* bbase = row_ptr + N + 1;                           // NB+1
    int* bsum = bbase + NB + 1;                             // NB
    int* counts = bsum + NB;                                // NB*NBLK = 1MB
    short* WT1 = (short*)(counts + NB * NBLK);              // 128*128 bf16
    short* WT2 = WT1 + 128 * 128;                           // 128*128 bf16

    unsigned short* S1 = (unsigned short*)d_out;  // bf16 layer-1 act (front 25.6MB of out)
    float* S2 = out;                              // fp32 layer-2 spmm result (full out)

    const dim3 blk(256);
    const int nGrid = (N + 255) / 256;
    const int ngroups = (N + 15) / 16;
    const int gemmGrid = (ngroups + 7) / 8;   // ~2 groups per wave

    // ---- weight transpose+bf16 (tiny, once per call)
    prep_wt2<<<128, blk, 0, stream>>>(W1, WT1, W2, WT2);

    // ---- CSR build (atomic-free radix partition; LDS atomics only)
    radix_count<<<NBLK, blk, 0, stream>>>(edst, counts, E, rpb, chunk);
    radix_scan_rel<<<NB, blk, 0, stream>>>(counts, bsum);
    radix_base<<<1, NB, 0, stream>>>(bsum, bbase, row_ptr, E, N);
    radix_scatter<<<NBLK, blk, 0, stream>>>(esrc, edst, ew, counts, bbase,
                                            tmp_sw, tmp_lr, E, rpb, chunk);
    bucket_sort<<<NB, blk, 0, stream>>>(tmp_lr, tmp_sw, bbase, ep, row_ptr, N, rpb);

    // ---- graph boundaries from sorted gid
    bounds_kernel<<<nGrid, blk, 0, stream>>>(gid, gptr, N);

    // ---- pipeline
    // A1 = feat @ W1 (bf16)
    gemm_mfma_f32in<<<gemmGrid, blk, 0, stream>>>(feat, WT1, (short*)A, N);
    // S1 = bf16(relu(spmm(A1) + b1))   [fused epilogue]
    spmm_csr<true><<<(N + 15) / 16, blk, 0, stream>>>((const uint4*)A, (const long long*)ep,
                                                      row_ptr, b1, S1, N);
    // A2 = S1 @ W2 (pure bf16 GEMM)
    gemm_mfma_bf16in<<<gemmGrid, blk, 0, stream>>>(S1, WT2, (short*)A, N);
    // S2 = spmm(A2) fp32  (b2 added in pool)
    spmm_csr<false><<<(N + 15) / 16, blk, 0, stream>>>((const uint4*)A, (const long long*)ep,
                                                       row_ptr, nullptr, S2, N);

    // ---- per-graph mean pool + FF + scatter
    pool_kernel<<<G, 512, 0, stream>>>(S2, gptr, b2, pooled);
    ff_kernel<<<G, 128, 0, stream>>>(pooled, ffW1, ffb1, ffW2, ffb2,
                                     ffW3, ffb3, ffWs, ffbs, ffo);
    scatter_kernel<<<(int)(((size_t)N * 32 + 255) / 256), blk, 0, stream>>>(ffo, gid, out, N);
}